// Round 6
// baseline (1529.400 us; speedup 1.0000x reference)
//
#include <hip/hip_runtime.h>
#include <hip/hip_fp16.h>

typedef _Float16 f16;
typedef __attribute__((ext_vector_type(2))) _Float16 f16x2;
typedef __attribute__((ext_vector_type(4))) _Float16 f16x4;
typedef __attribute__((ext_vector_type(8))) _Float16 f16x8;
typedef __attribute__((ext_vector_type(4))) float f32x4;

constexpr int BATCH = 64;
constexpr int TLEN  = 2048;
constexpr int NIN   = 128;
constexpr int NHID  = 256;
constexpr int NOUT  = 128;
constexpr long MROWS = (long)BATCH * TLEN;   // 131072
constexpr float CSC = 2.8853900817779268f;   // 2*log2(e): 2^(CSC*z) = e^(2z)

__device__ __forceinline__ float exp2f_hw(float x) {
#if __has_builtin(__builtin_amdgcn_exp2f)
  return __builtin_amdgcn_exp2f(x);
#else
  return __expf(x * 0.6931471805599453f);
#endif
}
__device__ __forceinline__ float rcp_hw(float x) {
#if __has_builtin(__builtin_amdgcn_rcpf)
  return __builtin_amdgcn_rcpf(x);
#else
  return 1.0f / x;
#endif
}
// barrier that makes LDS writes visible WITHOUT draining vmcnt (global
// stores / prefetch loads keep flying across steps)
__device__ __forceinline__ void barrier_lds() {
  asm volatile("s_waitcnt lgkmcnt(0)" ::: "memory");
  __builtin_amdgcn_s_barrier();
  asm volatile("" ::: "memory");
}

// ---------------------------------------------------------------------------
// Weight convert + hi/lo split. Whh pre-scaled by CSC (tanh exp2 fold).
// f16 layout: WinH[32768] WinL[32768] WihH[65536] WihL[65536] Whh[65536] Wout[32768]
// ---------------------------------------------------------------------------
__global__ void cvt_weights(const float* __restrict__ Win, const float* __restrict__ Wih,
                            const float* __restrict__ Whh, const float* __restrict__ Wout,
                            f16* __restrict__ dst) {
  int i = blockIdx.x * blockDim.x + threadIdx.x;
  if (i < 32768) {
    float v = Win[i]; f16 h = (f16)v;
    dst[i] = h; dst[32768 + i] = (f16)(v - (float)h);
  } else if (i < 98304) {
    int j = i - 32768; float v = Wih[j]; f16 h = (f16)v;
    dst[65536 + j] = h; dst[131072 + j] = (f16)(v - (float)h);
  } else if (i < 163840) {
    int j = i - 98304; dst[196608 + j] = (f16)(CSC * Whh[j]);
  } else if (i < 196608) {
    int j = i - 163840; dst[262144 + j] = (f16)Wout[j];
  }
}

// ---------------------------------------------------------------------------
// GEMM: C[m,n] = act( sum_k A[m,k]*W[n,k] + bias[n] )   (baseline, proven)
// ---------------------------------------------------------------------------
constexpr int BM = 64, BN = 64, BK = 64;

template<int MODE>
__global__ __launch_bounds__(256)
void gemm_kernel(const void* __restrict__ Ap, const void* __restrict__ Ap2,
                 const f16* __restrict__ Bh_, const f16* __restrict__ Bl_,
                 const float* __restrict__ bias, const float* __restrict__ bias2,
                 void* __restrict__ Cp, void* __restrict__ Cp2,
                 int K, int N) {
  __shared__ __align__(16) f16 Ah[BM][BK + 8];
  __shared__ __align__(16) f16 Al[BM][BK + 8];
  __shared__ __align__(16) f16 Bh[BN][BK + 8];
  __shared__ __align__(16) f16 Bl[BN][BK + 8];

  const int tid  = threadIdx.x;
  const int lane = tid & 63;
  const int wid  = tid >> 6;
  const int wm = wid >> 1, wn = wid & 1;
  const long row0 = (long)blockIdx.x * BM;
  const int  col0 = blockIdx.y * BN;
  const int r  = tid >> 2;
  const int cc = (tid & 3) * 16;

  f32x4 acc[2][2] = {};

  for (int k0 = 0; k0 < K; k0 += BK) {
    if constexpr (MODE == 1) {
      const float* src = (const float*)Ap + (row0 + r) * (long)K + k0 + cc;
      #pragma unroll
      for (int q = 0; q < 4; ++q) {
        float4 v = ((const float4*)src)[q];
        f16 h0 = (f16)v.x, h1 = (f16)v.y, h2 = (f16)v.z, h3 = (f16)v.w;
        Ah[r][cc + 4*q + 0] = h0;  Al[r][cc + 4*q + 0] = (f16)(v.x - (float)h0);
        Ah[r][cc + 4*q + 1] = h1;  Al[r][cc + 4*q + 1] = (f16)(v.y - (float)h1);
        Ah[r][cc + 4*q + 2] = h2;  Al[r][cc + 4*q + 2] = (f16)(v.z - (float)h2);
        Ah[r][cc + 4*q + 3] = h3;  Al[r][cc + 4*q + 3] = (f16)(v.w - (float)h3);
      }
    } else if constexpr (MODE == 2) {
      const f16* sh = (const f16*)Ap  + (row0 + r) * (long)K + k0 + cc;
      const f16* sl = (const f16*)Ap2 + (row0 + r) * (long)K + k0 + cc;
      *(uint4*)&Ah[r][cc]     = *(const uint4*)sh;
      *(uint4*)&Ah[r][cc + 8] = *(const uint4*)(sh + 8);
      *(uint4*)&Al[r][cc]     = *(const uint4*)sl;
      *(uint4*)&Al[r][cc + 8] = *(const uint4*)(sl + 8);
    } else {
      const f16* sh = (const f16*)Ap + (row0 + r) * (long)K + k0 + cc;
      *(uint4*)&Ah[r][cc]     = *(const uint4*)sh;
      *(uint4*)&Ah[r][cc + 8] = *(const uint4*)(sh + 8);
    }
    {
      const f16* sh = Bh_ + (col0 + r) * (long)K + k0 + cc;
      *(uint4*)&Bh[r][cc]     = *(const uint4*)sh;
      *(uint4*)&Bh[r][cc + 8] = *(const uint4*)(sh + 8);
      if constexpr (MODE != 3) {
        const f16* sl = Bl_ + (col0 + r) * (long)K + k0 + cc;
        *(uint4*)&Bl[r][cc]     = *(const uint4*)sl;
        *(uint4*)&Bl[r][cc + 8] = *(const uint4*)(sl + 8);
      }
    }
    __syncthreads();

    #pragma unroll
    for (int ks = 0; ks < BK / 32; ++ks) {
      const int ko = ks * 32 + (lane >> 4) * 8;
      const int ra = wm * 32 + (lane & 15);
      const int rb = wn * 32 + (lane & 15);
      f16x8 a0 = *(const f16x8*)&Ah[ra][ko];
      f16x8 a1 = *(const f16x8*)&Ah[ra + 16][ko];
      f16x8 b0 = *(const f16x8*)&Bh[rb][ko];
      f16x8 b1 = *(const f16x8*)&Bh[rb + 16][ko];
      acc[0][0] = __builtin_amdgcn_mfma_f32_16x16x32_f16(a0, b0, acc[0][0], 0, 0, 0);
      acc[0][1] = __builtin_amdgcn_mfma_f32_16x16x32_f16(a0, b1, acc[0][1], 0, 0, 0);
      acc[1][0] = __builtin_amdgcn_mfma_f32_16x16x32_f16(a1, b0, acc[1][0], 0, 0, 0);
      acc[1][1] = __builtin_amdgcn_mfma_f32_16x16x32_f16(a1, b1, acc[1][1], 0, 0, 0);
      if constexpr (MODE != 3) {
        f16x8 la0 = *(const f16x8*)&Al[ra][ko];
        f16x8 la1 = *(const f16x8*)&Al[ra + 16][ko];
        f16x8 lb0 = *(const f16x8*)&Bl[rb][ko];
        f16x8 lb1 = *(const f16x8*)&Bl[rb + 16][ko];
        acc[0][0] = __builtin_amdgcn_mfma_f32_16x16x32_f16(a0, lb0, acc[0][0], 0, 0, 0);
        acc[0][0] = __builtin_amdgcn_mfma_f32_16x16x32_f16(la0, b0, acc[0][0], 0, 0, 0);
        acc[0][1] = __builtin_amdgcn_mfma_f32_16x16x32_f16(a0, lb1, acc[0][1], 0, 0, 0);
        acc[0][1] = __builtin_amdgcn_mfma_f32_16x16x32_f16(la0, b1, acc[0][1], 0, 0, 0);
        acc[1][0] = __builtin_amdgcn_mfma_f32_16x16x32_f16(a1, lb0, acc[1][0], 0, 0, 0);
        acc[1][0] = __builtin_amdgcn_mfma_f32_16x16x32_f16(la1, b0, acc[1][0], 0, 0, 0);
        acc[1][1] = __builtin_amdgcn_mfma_f32_16x16x32_f16(a1, lb1, acc[1][1], 0, 0, 0);
        acc[1][1] = __builtin_amdgcn_mfma_f32_16x16x32_f16(la1, b1, acc[1][1], 0, 0, 0);
      }
    }
    __syncthreads();
  }

  #pragma unroll
  for (int mi = 0; mi < 2; ++mi)
    #pragma unroll
    for (int ni = 0; ni < 2; ++ni)
      #pragma unroll
      for (int q = 0; q < 4; ++q) {
        long row = row0 + wm * 32 + mi * 16 + (lane >> 4) * 4 + q;
        int  col = col0 + wn * 32 + ni * 16 + (lane & 15);
        if constexpr (MODE == 1) {
          float v = fmaxf(acc[mi][ni][q] + bias[col], 0.0f);
          f16 h = (f16)v;
          ((f16*)Cp )[row * (long)N + col] = h;
          ((f16*)Cp2)[row * (long)N + col] = (f16)(v - (float)h);
        } else if constexpr (MODE == 2) {
          float v = (acc[mi][ni][q] + bias[col] + bias2[col]) * CSC;
          ((float*)Cp)[row * (long)N + col] = v;
        } else {
          ((float*)Cp)[row * (long)N + col] = acc[mi][ni][q] + bias[col];
        }
      }
}

// ---------------------------------------------------------------------------
// Recurrence R18: MFMA matvec at FULL 64-CU parallelism (1 block = 1 batch),
// weights register-resident as MFMA A-operands.
//
// Why: R12/R15/R16/R17 (fdot2) all re-streamed the full 128 KB Whh per
// CU-step (VGPR_Count 32-52 proves no residency; step 1040-1400 cyc matches
// L1/L2 stream time, invariant across VALU/LDS restructures). The ONLY
// variant that kept weights in VGPRs was R14 (VGPR=92) — weights as f16x8
// MFMA fragments. R14 was slow purely because 8 blocks starved aggregate
// throughput. R18 = R14's residency x R12's 64-block grid.
//
// Per block (512 thr, 8 waves): wave w owns output rows [32w,32w+32) as two
// 16-row tiles; A-frag wA[t][c] = Whh[(32w+16t+col)*256 + c*32 + kg*8 ..+8]
// (col=lane&15, kg=lane>>4; layout correctness-proven by R14's pass).
// B = h broadcast to all 16 cols: ds_read addr depends only on kg (4 distinct
// 16B addrs/wave instr, disjoint banks, 16-lane broadcast — conflict-free).
// All D columns then hold the SAME valid result: col0 lanes write next-h to
// LDS (ping-pong, plain linear 512B), col1 lanes write h16 global; cols 2-15
// redundant. MFMA cost: 16/wave/step, 2 indep 4-deep chains per tile.
// Epilogue z = aA+aB+pre (pre CSC-scaled, [b][t][g] layout, 4-deep rolling
// prefetch; last prefetches read <=4KB past pre into the allocated weights
// region — values unused). 1 lgkmcnt-only barrier/step.
// ---------------------------------------------------------------------------
#define RSTEP(S, SRC, DST, PA, PB) do {                                      \
  f16x8 hB[8];                                                               \
  _Pragma("unroll")                                                          \
  for (int c = 0; c < 8; ++c)                                                \
    hB[c] = *(const f16x8*)((SRC) + 64 * c + 16 * kg);                       \
  f32x4 aA0 = {0.f,0.f,0.f,0.f}, aB0 = {0.f,0.f,0.f,0.f};                    \
  f32x4 aA1 = {0.f,0.f,0.f,0.f}, aB1 = {0.f,0.f,0.f,0.f};                    \
  _Pragma("unroll")                                                          \
  for (int c = 0; c < 4; ++c) {                                              \
    aA0 = __builtin_amdgcn_mfma_f32_16x16x32_f16(wA[0][c],     hB[c],     aA0, 0, 0, 0); \
    aA1 = __builtin_amdgcn_mfma_f32_16x16x32_f16(wA[1][c],     hB[c],     aA1, 0, 0, 0); \
    aB0 = __builtin_amdgcn_mfma_f32_16x16x32_f16(wA[0][c + 4], hB[c + 4], aB0, 0, 0, 0); \
    aB1 = __builtin_amdgcn_mfma_f32_16x16x32_f16(wA[1][c + 4], hB[c + 4], aB1, 0, 0, 0); \
  }                                                                          \
  f16x4 h0, h1;                                                              \
  _Pragma("unroll")                                                          \
  for (int q = 0; q < 4; ++q) {                                              \
    float z0 = aA0[q] + aB0[q] + (PA)[q];                                    \
    float z1 = aA1[q] + aB1[q] + (PB)[q];                                    \
    float e0 = exp2f_hw(z0);                                                 \
    float e1 = exp2f_hw(z1);                                                 \
    float v0 = fmaxf(fmaf(-2.0f, rcp_hw(e0 + 1.0f), 1.0f), 0.0f);            \
    float v1 = fmaxf(fmaf(-2.0f, rcp_hw(e1 + 1.0f), 1.0f), 0.0f);            \
    h0[q] = (f16)v0;                                                         \
    h1[q] = (f16)v1;                                                         \
  }                                                                          \
  if (col == 0) {                                                            \
    *(f16x4*)((DST) + wo)      = h0;   /* LDS next-h rows g0..g0+3   */      \
    *(f16x4*)((DST) + wo + 32) = h1;   /* LDS next-h rows g0+16..+19 */      \
  } else if (col == 1) {                                                     \
    *(f16x4*)(hp + (S) * 256)      = h0;   /* h16 global tile 0 */           \
    *(f16x4*)(hp + (S) * 256 + 16) = h1;   /* h16 global tile 1 */           \
  }                                                                          \
} while (0)

__global__ __launch_bounds__(512, 1)
void rec_kernel(const float* __restrict__ pre, const f16* __restrict__ W2,
                f16* __restrict__ h16) {
  const int b    = blockIdx.x;          // batch
  const int tid  = threadIdx.x;
  const int lane = tid & 63;
  const int w    = tid >> 6;            // wave 0..7: output rows [32w,32w+32)
  const int col  = lane & 15;           // MFMA m/n-col index
  const int kg   = lane >> 4;           // 0..3: k-subgroup / D-row group

  __shared__ __align__(16) char hb[2][512];   // ping-pong h buffers (256 f16)

  // Stationary A-fragments: rows 32w+16t+col, k = c*32 + kg*8 .. +8
  f16x8 wA[2][8];
  #pragma unroll
  for (int t = 0; t < 2; ++t)
    #pragma unroll
    for (int c = 0; c < 8; ++c)
      wA[t][c] = *(const f16x8*)(W2 + (size_t)(32 * w + 16 * t + col) * 256
                                 + c * 32 + kg * 8);

  // zero both h buffers (h_0 = 0)
  if (tid < 256) ((unsigned int*)&hb[0][0])[tid] = 0u;
  __syncthreads();

  const int wo = 64 * w + 8 * kg;       // LDS byte offset of rows g0..g0+3
  const int g0 = 32 * w + 4 * kg;       // first owned output row (tile 0)

  const float* pp  = pre + (size_t)b * TLEN * 256 + g0;
  f16*         hp  = h16 + (size_t)b * TLEN * 256 + g0;
  const float* ppf = pp + 1024;         // t+4 prefetch pointer

  f32x4 p00 = *(const f32x4*)(pp);
  f32x4 p01 = *(const f32x4*)(pp + 16);
  f32x4 p10 = *(const f32x4*)(pp + 256);
  f32x4 p11 = *(const f32x4*)(pp + 272);
  f32x4 p20 = *(const f32x4*)(pp + 512);
  f32x4 p21 = *(const f32x4*)(pp + 528);
  f32x4 p30 = *(const f32x4*)(pp + 768);
  f32x4 p31 = *(const f32x4*)(pp + 784);

  const char* hb0 = &hb[0][0];
  char*       hb1 = &hb[1][0];

  #pragma unroll 1
  for (int t = 0; t < TLEN; t += 4) {
    // issue next-quad prefetch early; lands during these 4 steps
    f32x4 n00 = *(const f32x4*)(ppf);
    f32x4 n01 = *(const f32x4*)(ppf + 16);
    f32x4 n10 = *(const f32x4*)(ppf + 256);
    f32x4 n11 = *(const f32x4*)(ppf + 272);
    f32x4 n20 = *(const f32x4*)(ppf + 512);
    f32x4 n21 = *(const f32x4*)(ppf + 528);
    f32x4 n30 = *(const f32x4*)(ppf + 768);
    f32x4 n31 = *(const f32x4*)(ppf + 784);
    RSTEP(0, hb0, hb1, p00, p01);
    barrier_lds();
    RSTEP(1, hb1, (char*)hb0, p10, p11);
    barrier_lds();
    RSTEP(2, hb0, hb1, p20, p21);
    barrier_lds();
    RSTEP(3, hb1, (char*)hb0, p30, p31);
    barrier_lds();
    p00 = n00; p01 = n01; p10 = n10; p11 = n11;
    p20 = n20; p21 = n21; p30 = n30; p31 = n31;
    ppf += 1024;
    hp  += 1024;
  }
}

// ---------------------------------------------------------------------------
// h16 -> f32 hidden (parallel, HBM-bound). Unchanged.
// ---------------------------------------------------------------------------
__global__ __launch_bounds__(256)
void cvt_h(const f16* __restrict__ src, float* __restrict__ dst, long n) {
  long i0 = ((long)blockIdx.x * 256 + threadIdx.x) * 8;
  long stride = (long)gridDim.x * 256 * 8;
  for (long i = i0; i < n; i += stride) {
    f16x8 v = *(const f16x8*)(src + i);
    float4 a = {(float)v[0], (float)v[1], (float)v[2], (float)v[3]};
    float4 bq = {(float)v[4], (float)v[5], (float)v[6], (float)v[7]};
    *(float4*)(dst + i) = a;
    *(float4*)(dst + i + 4) = bq;
  }
}

// ---------------------------------------------------------------------------
extern "C" void kernel_launch(void* const* d_in, const int* in_sizes, int n_in,
                              void* d_out, int out_size, void* d_ws, size_t ws_size,
                              hipStream_t stream) {
  const float* input = (const float*)d_in[0];
  const float* W_in  = (const float*)d_in[1];
  const float* b_in  = (const float*)d_in[2];
  const float* W_ih  = (const float*)d_in[3];
  const float* b_ih  = (const float*)d_in[4];
  const float* W_hh  = (const float*)d_in[5];
  const float* b_hh  = (const float*)d_in[6];
  const float* W_out = (const float*)d_in[7];
  const float* b_out = (const float*)d_in[8];

  float* hidden = (float*)d_out;                   // [64,2048,256] f32
  float* outp   = (float*)d_out + MROWS * NHID;    // [64,2048,128] f32

  char* ws = (char*)d_ws;
  const size_t xh_off  = 0;
  const size_t xl_off  = (size_t)MROWS * NHID * 2;       // 64 MiB
  const size_t pre_off = xl_off * 2;                     // 128 MiB in
  const size_t w_off   = pre_off + (size_t)MROWS * NHID * 4;
  const size_t need    = w_off + 294912ull * 2;
  if (ws_size < need) return;

  f16*   x_hi  = (f16*)(ws + xh_off);
  f16*   x_lo  = (f16*)(ws + xl_off);
  float* pre   = (float*)(ws + pre_off);                 // plain [b][t][g], scaled
  f16*   wbase = (f16*)(ws + w_off);
  f16 *WinH = wbase,           *WinL = wbase + 32768;
  f16 *WihH = wbase + 65536,   *WihL = wbase + 131072;
  f16 *Whh16 = wbase + 196608, *Wout16 = wbase + 262144;
  f16* h16 = x_hi;   // alias: x consumed by G2 before rec writes h16

  cvt_weights<<<768, 256, 0, stream>>>(W_in, W_ih, W_hh, W_out, wbase);

  dim3 g12((unsigned)(MROWS / BM), NHID / BN);
  gemm_kernel<1><<<g12, 256, 0, stream>>>(input, nullptr, WinH, WinL, b_in, nullptr,
                                          x_hi, x_lo, NIN, NHID);
  gemm_kernel<2><<<g12, 256, 0, stream>>>(x_hi, x_lo, WihH, WihL, b_ih, b_hh,
                                          pre, nullptr, NHID, NHID);

  rec_kernel<<<BATCH, 512, 0, stream>>>(pre, Whh16, h16);

  cvt_h<<<2048, 256, 0, stream>>>(h16, hidden, MROWS * NHID);

  dim3 g3((unsigned)(MROWS / BM), NOUT / BN);
  gemm_kernel<3><<<g3, 256, 0, stream>>>(h16, nullptr, Wout16, nullptr, b_out, nullptr,
                                         outp, nullptr, NHID, NOUT);
}

// Round 7
// 1425.730 us; speedup vs baseline: 1.0727x; 1.0727x over previous
//
#include <hip/hip_runtime.h>
#include <hip/hip_fp16.h>

typedef _Float16 f16;
typedef __attribute__((ext_vector_type(2))) _Float16 f16x2;
typedef __attribute__((ext_vector_type(4))) _Float16 f16x4;
typedef __attribute__((ext_vector_type(8))) _Float16 f16x8;
typedef __attribute__((ext_vector_type(4))) float f32x4;

constexpr int BATCH = 64;
constexpr int TLEN  = 2048;
constexpr int NIN   = 128;
constexpr int NHID  = 256;
constexpr int NOUT  = 128;
constexpr long MROWS = (long)BATCH * TLEN;   // 131072
constexpr float CSC = 2.8853900817779268f;   // 2*log2(e): 2^(CSC*z) = e^(2z)

__device__ __forceinline__ float exp2f_hw(float x) {
#if __has_builtin(__builtin_amdgcn_exp2f)
  return __builtin_amdgcn_exp2f(x);
#else
  return __expf(x * 0.6931471805599453f);
#endif
}
__device__ __forceinline__ float rcp_hw(float x) {
#if __has_builtin(__builtin_amdgcn_rcpf)
  return __builtin_amdgcn_rcpf(x);
#else
  return 1.0f / x;
#endif
}
// barrier that makes LDS writes visible WITHOUT draining vmcnt (global
// stores / prefetch loads keep flying across steps)
__device__ __forceinline__ void barrier_lds() {
  asm volatile("s_waitcnt lgkmcnt(0)" ::: "memory");
  __builtin_amdgcn_s_barrier();
  asm volatile("" ::: "memory");
}

// ---------------------------------------------------------------------------
// Weight convert + hi/lo split. Whh pre-scaled by CSC (tanh exp2 fold).
// f16 layout: WinH[32768] WinL[32768] WihH[65536] WihL[65536] Whh[65536] Wout[32768]
// ---------------------------------------------------------------------------
__global__ void cvt_weights(const float* __restrict__ Win, const float* __restrict__ Wih,
                            const float* __restrict__ Whh, const float* __restrict__ Wout,
                            f16* __restrict__ dst) {
  int i = blockIdx.x * blockDim.x + threadIdx.x;
  if (i < 32768) {
    float v = Win[i]; f16 h = (f16)v;
    dst[i] = h; dst[32768 + i] = (f16)(v - (float)h);
  } else if (i < 98304) {
    int j = i - 32768; float v = Wih[j]; f16 h = (f16)v;
    dst[65536 + j] = h; dst[131072 + j] = (f16)(v - (float)h);
  } else if (i < 163840) {
    int j = i - 98304; dst[196608 + j] = (f16)(CSC * Whh[j]);
  } else if (i < 196608) {
    int j = i - 163840; dst[262144 + j] = (f16)Wout[j];
  }
}

// ---------------------------------------------------------------------------
// GEMM: C[m,n] = act( sum_k A[m,k]*W[n,k] + bias[n] )   (baseline, proven)
// ---------------------------------------------------------------------------
constexpr int BM = 64, BN = 64, BK = 64;

template<int MODE>
__global__ __launch_bounds__(256)
void gemm_kernel(const void* __restrict__ Ap, const void* __restrict__ Ap2,
                 const f16* __restrict__ Bh_, const f16* __restrict__ Bl_,
                 const float* __restrict__ bias, const float* __restrict__ bias2,
                 void* __restrict__ Cp, void* __restrict__ Cp2,
                 int K, int N) {
  __shared__ __align__(16) f16 Ah[BM][BK + 8];
  __shared__ __align__(16) f16 Al[BM][BK + 8];
  __shared__ __align__(16) f16 Bh[BN][BK + 8];
  __shared__ __align__(16) f16 Bl[BN][BK + 8];

  const int tid  = threadIdx.x;
  const int lane = tid & 63;
  const int wid  = tid >> 6;
  const int wm = wid >> 1, wn = wid & 1;
  const long row0 = (long)blockIdx.x * BM;
  const int  col0 = blockIdx.y * BN;
  const int r  = tid >> 2;
  const int cc = (tid & 3) * 16;

  f32x4 acc[2][2] = {};

  for (int k0 = 0; k0 < K; k0 += BK) {
    if constexpr (MODE == 1) {
      const float* src = (const float*)Ap + (row0 + r) * (long)K + k0 + cc;
      #pragma unroll
      for (int q = 0; q < 4; ++q) {
        float4 v = ((const float4*)src)[q];
        f16 h0 = (f16)v.x, h1 = (f16)v.y, h2 = (f16)v.z, h3 = (f16)v.w;
        Ah[r][cc + 4*q + 0] = h0;  Al[r][cc + 4*q + 0] = (f16)(v.x - (float)h0);
        Ah[r][cc + 4*q + 1] = h1;  Al[r][cc + 4*q + 1] = (f16)(v.y - (float)h1);
        Ah[r][cc + 4*q + 2] = h2;  Al[r][cc + 4*q + 2] = (f16)(v.z - (float)h2);
        Ah[r][cc + 4*q + 3] = h3;  Al[r][cc + 4*q + 3] = (f16)(v.w - (float)h3);
      }
    } else if constexpr (MODE == 2) {
      const f16* sh = (const f16*)Ap  + (row0 + r) * (long)K + k0 + cc;
      const f16* sl = (const f16*)Ap2 + (row0 + r) * (long)K + k0 + cc;
      *(uint4*)&Ah[r][cc]     = *(const uint4*)sh;
      *(uint4*)&Ah[r][cc + 8] = *(const uint4*)(sh + 8);
      *(uint4*)&Al[r][cc]     = *(const uint4*)sl;
      *(uint4*)&Al[r][cc + 8] = *(const uint4*)(sl + 8);
    } else {
      const f16* sh = (const f16*)Ap + (row0 + r) * (long)K + k0 + cc;
      *(uint4*)&Ah[r][cc]     = *(const uint4*)sh;
      *(uint4*)&Ah[r][cc + 8] = *(const uint4*)(sh + 8);
    }
    {
      const f16* sh = Bh_ + (col0 + r) * (long)K + k0 + cc;
      *(uint4*)&Bh[r][cc]     = *(const uint4*)sh;
      *(uint4*)&Bh[r][cc + 8] = *(const uint4*)(sh + 8);
      if constexpr (MODE != 3) {
        const f16* sl = Bl_ + (col0 + r) * (long)K + k0 + cc;
        *(uint4*)&Bl[r][cc]     = *(const uint4*)sl;
        *(uint4*)&Bl[r][cc + 8] = *(const uint4*)(sl + 8);
      }
    }
    __syncthreads();

    #pragma unroll
    for (int ks = 0; ks < BK / 32; ++ks) {
      const int ko = ks * 32 + (lane >> 4) * 8;
      const int ra = wm * 32 + (lane & 15);
      const int rb = wn * 32 + (lane & 15);
      f16x8 a0 = *(const f16x8*)&Ah[ra][ko];
      f16x8 a1 = *(const f16x8*)&Ah[ra + 16][ko];
      f16x8 b0 = *(const f16x8*)&Bh[rb][ko];
      f16x8 b1 = *(const f16x8*)&Bh[rb + 16][ko];
      acc[0][0] = __builtin_amdgcn_mfma_f32_16x16x32_f16(a0, b0, acc[0][0], 0, 0, 0);
      acc[0][1] = __builtin_amdgcn_mfma_f32_16x16x32_f16(a0, b1, acc[0][1], 0, 0, 0);
      acc[1][0] = __builtin_amdgcn_mfma_f32_16x16x32_f16(a1, b0, acc[1][0], 0, 0, 0);
      acc[1][1] = __builtin_amdgcn_mfma_f32_16x16x32_f16(a1, b1, acc[1][1], 0, 0, 0);
      if constexpr (MODE != 3) {
        f16x8 la0 = *(const f16x8*)&Al[ra][ko];
        f16x8 la1 = *(const f16x8*)&Al[ra + 16][ko];
        f16x8 lb0 = *(const f16x8*)&Bl[rb][ko];
        f16x8 lb1 = *(const f16x8*)&Bl[rb + 16][ko];
        acc[0][0] = __builtin_amdgcn_mfma_f32_16x16x32_f16(a0, lb0, acc[0][0], 0, 0, 0);
        acc[0][0] = __builtin_amdgcn_mfma_f32_16x16x32_f16(la0, b0, acc[0][0], 0, 0, 0);
        acc[0][1] = __builtin_amdgcn_mfma_f32_16x16x32_f16(a0, lb1, acc[0][1], 0, 0, 0);
        acc[0][1] = __builtin_amdgcn_mfma_f32_16x16x32_f16(la0, b1, acc[0][1], 0, 0, 0);
        acc[1][0] = __builtin_amdgcn_mfma_f32_16x16x32_f16(a1, lb0, acc[1][0], 0, 0, 0);
        acc[1][0] = __builtin_amdgcn_mfma_f32_16x16x32_f16(la1, b0, acc[1][0], 0, 0, 0);
        acc[1][1] = __builtin_amdgcn_mfma_f32_16x16x32_f16(a1, lb1, acc[1][1], 0, 0, 0);
        acc[1][1] = __builtin_amdgcn_mfma_f32_16x16x32_f16(la1, b1, acc[1][1], 0, 0, 0);
      }
    }
    __syncthreads();
  }

  #pragma unroll
  for (int mi = 0; mi < 2; ++mi)
    #pragma unroll
    for (int ni = 0; ni < 2; ++ni)
      #pragma unroll
      for (int q = 0; q < 4; ++q) {
        long row = row0 + wm * 32 + mi * 16 + (lane >> 4) * 4 + q;
        int  col = col0 + wn * 32 + ni * 16 + (lane & 15);
        if constexpr (MODE == 1) {
          float v = fmaxf(acc[mi][ni][q] + bias[col], 0.0f);
          f16 h = (f16)v;
          ((f16*)Cp )[row * (long)N + col] = h;
          ((f16*)Cp2)[row * (long)N + col] = (f16)(v - (float)h);
        } else if constexpr (MODE == 2) {
          float v = (acc[mi][ni][q] + bias[col] + bias2[col]) * CSC;
          ((float*)Cp)[row * (long)N + col] = v;
        } else {
          ((float*)Cp)[row * (long)N + col] = acc[mi][ni][q] + bias[col];
        }
      }
}

// ---------------------------------------------------------------------------
// Recurrence R19 = R18 (MFMA broadcast matvec, 64 blocks — correctness-proven)
// + loop-carried weight residency + halved register demand.
//
// R18 failure mode (VGPR=80 vs ~190 live): allocator remat'ed/spilled around
// a once-only pin; weights+working set streamed from scratch/L2 every step
// (1540 cyc/step). Fixes here:
//  (1) asm "+v" pin of all 16 wA fragments INSIDE the t-loop: the values
//      become loop-carried (redefined each iteration) -> rematerialization
//      from W2 is illegal, and spilling would cost 64 reloads x 2048 iters,
//      which the allocator's cost model rejects. This is the difference from
//      R16/R18's outside-the-loop pins.
//  (2) prefetch depth 4->2, unroll 4->2: peak live set ~160 regs (wA 64 +
//      hB 32 + acc 16 + p/n 32 + misc), comfortably under the 256 cap.
//  (3) __launch_bounds__(512, 2): allocation hard-capped at 256 so the
//      8-wave block always co-resides at 2 waves/SIMD.
// Per step: 8 broadcast ds_read_b128 (hB, 4 unique addrs/instr) + 16 MFMA in
// 4 indep 4-deep chains + 8-output activation + LDS/global h writes; one
// lgkmcnt-only barrier. pre [b][t][g], depth-2 rolling prefetch (last iter
// reads 2KB past pre into the allocated weights region — values unused).
// ---------------------------------------------------------------------------
#define RSTEP(S, SRC, DST, PA, PB) do {                                      \
  f16x8 hB[8];                                                               \
  _Pragma("unroll")                                                          \
  for (int c = 0; c < 8; ++c)                                                \
    hB[c] = *(const f16x8*)((SRC) + 64 * c + 16 * kg);                       \
  f32x4 aA0 = {0.f,0.f,0.f,0.f}, aB0 = {0.f,0.f,0.f,0.f};                    \
  f32x4 aA1 = {0.f,0.f,0.f,0.f}, aB1 = {0.f,0.f,0.f,0.f};                    \
  _Pragma("unroll")                                                          \
  for (int c = 0; c < 4; ++c) {                                              \
    aA0 = __builtin_amdgcn_mfma_f32_16x16x32_f16(wA[0][c],     hB[c],     aA0, 0, 0, 0); \
    aA1 = __builtin_amdgcn_mfma_f32_16x16x32_f16(wA[1][c],     hB[c],     aA1, 0, 0, 0); \
    aB0 = __builtin_amdgcn_mfma_f32_16x16x32_f16(wA[0][c + 4], hB[c + 4], aB0, 0, 0, 0); \
    aB1 = __builtin_amdgcn_mfma_f32_16x16x32_f16(wA[1][c + 4], hB[c + 4], aB1, 0, 0, 0); \
  }                                                                          \
  f16x4 h0, h1;                                                              \
  _Pragma("unroll")                                                          \
  for (int q = 0; q < 4; ++q) {                                              \
    float z0 = aA0[q] + aB0[q] + (PA)[q];                                    \
    float z1 = aA1[q] + aB1[q] + (PB)[q];                                    \
    float e0 = exp2f_hw(z0);                                                 \
    float e1 = exp2f_hw(z1);                                                 \
    float v0 = fmaxf(fmaf(-2.0f, rcp_hw(e0 + 1.0f), 1.0f), 0.0f);            \
    float v1 = fmaxf(fmaf(-2.0f, rcp_hw(e1 + 1.0f), 1.0f), 0.0f);            \
    h0[q] = (f16)v0;                                                         \
    h1[q] = (f16)v1;                                                         \
  }                                                                          \
  if (col == 0) {                                                            \
    *(f16x4*)((DST) + wo)      = h0;   /* LDS next-h rows g0..g0+3   */      \
    *(f16x4*)((DST) + wo + 32) = h1;   /* LDS next-h rows g0+16..+19 */      \
  } else if (col == 1) {                                                     \
    *(f16x4*)(hp + (S) * 256)      = h0;   /* h16 global tile 0 */           \
    *(f16x4*)(hp + (S) * 256 + 16) = h1;   /* h16 global tile 1 */           \
  }                                                                          \
} while (0)

__global__ __launch_bounds__(512, 2)
void rec_kernel(const float* __restrict__ pre, const f16* __restrict__ W2,
                f16* __restrict__ h16) {
  const int b    = blockIdx.x;          // batch
  const int tid  = threadIdx.x;
  const int lane = tid & 63;
  const int w    = tid >> 6;            // wave 0..7: output rows [32w,32w+32)
  const int col  = lane & 15;           // MFMA m/n-col index
  const int kg   = lane >> 4;           // 0..3: k-subgroup / D-row group

  __shared__ __align__(16) char hb[2][512];   // ping-pong h buffers (256 f16)

  // Stationary A-fragments: rows 32w+16t+col, k = c*32 + kg*8 .. +8
  f16x8 wA[2][8];
  #pragma unroll
  for (int t = 0; t < 2; ++t)
    #pragma unroll
    for (int c = 0; c < 8; ++c)
      wA[t][c] = *(const f16x8*)(W2 + (size_t)(32 * w + 16 * t + col) * 256
                                 + c * 32 + kg * 8);

  // zero both h buffers (h_0 = 0)
  if (tid < 256) ((unsigned int*)&hb[0][0])[tid] = 0u;
  __syncthreads();

  const int wo = 64 * w + 8 * kg;       // LDS byte offset of rows g0..g0+3
  const int g0 = 32 * w + 4 * kg;       // first owned output row (tile 0)

  const float* pp  = pre + (size_t)b * TLEN * 256 + g0;
  f16*         hp  = h16 + (size_t)b * TLEN * 256 + g0;
  const float* ppf = pp + 512;          // t+2 prefetch pointer

  f32x4 p00 = *(const f32x4*)(pp);
  f32x4 p01 = *(const f32x4*)(pp + 16);
  f32x4 p10 = *(const f32x4*)(pp + 256);
  f32x4 p11 = *(const f32x4*)(pp + 272);

  const char* hb0 = &hb[0][0];
  char*       hb1 = &hb[1][0];

  #pragma unroll 1
  for (int t = 0; t < TLEN; t += 2) {
    // loop-carried pin: wA must be in VGPRs here EVERY iteration; remat from
    // W2 is illegal (value is no longer the invariant-load result), spill
    // would cost 64 reloads/iter. This is the residency forcing move.
    asm volatile("" : "+v"(wA[0][0]), "+v"(wA[0][1]), "+v"(wA[0][2]), "+v"(wA[0][3]),
                      "+v"(wA[0][4]), "+v"(wA[0][5]), "+v"(wA[0][6]), "+v"(wA[0][7]),
                      "+v"(wA[1][0]), "+v"(wA[1][1]), "+v"(wA[1][2]), "+v"(wA[1][3]),
                      "+v"(wA[1][4]), "+v"(wA[1][5]), "+v"(wA[1][6]), "+v"(wA[1][7]));
    // issue next-pair prefetch early; lands during these 2 steps
    f32x4 n00 = *(const f32x4*)(ppf);
    f32x4 n01 = *(const f32x4*)(ppf + 16);
    f32x4 n10 = *(const f32x4*)(ppf + 256);
    f32x4 n11 = *(const f32x4*)(ppf + 272);
    RSTEP(0, hb0, hb1, p00, p01);
    barrier_lds();
    RSTEP(1, hb1, (char*)hb0, p10, p11);
    barrier_lds();
    p00 = n00; p01 = n01; p10 = n10; p11 = n11;
    ppf += 512;
    hp  += 512;
  }
}

// ---------------------------------------------------------------------------
// h16 -> f32 hidden (parallel, HBM-bound). Unchanged.
// ---------------------------------------------------------------------------
__global__ __launch_bounds__(256)
void cvt_h(const f16* __restrict__ src, float* __restrict__ dst, long n) {
  long i0 = ((long)blockIdx.x * 256 + threadIdx.x) * 8;
  long stride = (long)gridDim.x * 256 * 8;
  for (long i = i0; i < n; i += stride) {
    f16x8 v = *(const f16x8*)(src + i);
    float4 a = {(float)v[0], (float)v[1], (float)v[2], (float)v[3]};
    float4 bq = {(float)v[4], (float)v[5], (float)v[6], (float)v[7]};
    *(float4*)(dst + i) = a;
    *(float4*)(dst + i + 4) = bq;
  }
}

// ---------------------------------------------------------------------------
extern "C" void kernel_launch(void* const* d_in, const int* in_sizes, int n_in,
                              void* d_out, int out_size, void* d_ws, size_t ws_size,
                              hipStream_t stream) {
  const float* input = (const float*)d_in[0];
  const float* W_in  = (const float*)d_in[1];
  const float* b_in  = (const float*)d_in[2];
  const float* W_ih  = (const float*)d_in[3];
  const float* b_ih  = (const float*)d_in[4];
  const float* W_hh  = (const float*)d_in[5];
  const float* b_hh  = (const float*)d_in[6];
  const float* W_out = (const float*)d_in[7];
  const float* b_out = (const float*)d_in[8];

  float* hidden = (float*)d_out;                   // [64,2048,256] f32
  float* outp   = (float*)d_out + MROWS * NHID;    // [64,2048,128] f32

  char* ws = (char*)d_ws;
  const size_t xh_off  = 0;
  const size_t xl_off  = (size_t)MROWS * NHID * 2;       // 64 MiB
  const size_t pre_off = xl_off * 2;                     // 128 MiB in
  const size_t w_off   = pre_off + (size_t)MROWS * NHID * 4;
  const size_t need    = w_off + 294912ull * 2;
  if (ws_size < need) return;

  f16*   x_hi  = (f16*)(ws + xh_off);
  f16*   x_lo  = (f16*)(ws + xl_off);
  float* pre   = (float*)(ws + pre_off);                 // plain [b][t][g], scaled
  f16*   wbase = (f16*)(ws + w_off);
  f16 *WinH = wbase,           *WinL = wbase + 32768;
  f16 *WihH = wbase + 65536,   *WihL = wbase + 131072;
  f16 *Whh16 = wbase + 196608, *Wout16 = wbase + 262144;
  f16* h16 = x_hi;   // alias: x consumed by G2 before rec writes h16

  cvt_weights<<<768, 256, 0, stream>>>(W_in, W_ih, W_hh, W_out, wbase);

  dim3 g12((unsigned)(MROWS / BM), NHID / BN);
  gemm_kernel<1><<<g12, 256, 0, stream>>>(input, nullptr, WinH, WinL, b_in, nullptr,
                                          x_hi, x_lo, NIN, NHID);
  gemm_kernel<2><<<g12, 256, 0, stream>>>(x_hi, x_lo, WihH, WihL, b_ih, b_hh,
                                          pre, nullptr, NHID, NHID);

  rec_kernel<<<BATCH, 512, 0, stream>>>(pre, Whh16, h16);

  cvt_h<<<2048, 256, 0, stream>>>(h16, hidden, MROWS * NHID);

  dim3 g3((unsigned)(MROWS / BM), NOUT / BN);
  gemm_kernel<3><<<g3, 256, 0, stream>>>(h16, nullptr, Wout16, nullptr, b_out, nullptr,
                                         outp, nullptr, NHID, NOUT);
}

// Round 8
// 1051.275 us; speedup vs baseline: 1.4548x; 1.3562x over previous
//
#include <hip/hip_runtime.h>
#include <hip/hip_fp16.h>

typedef _Float16 f16;
typedef __attribute__((ext_vector_type(2))) _Float16 f16x2;
typedef __attribute__((ext_vector_type(8))) _Float16 f16x8;
typedef __attribute__((ext_vector_type(4))) float f32x4;

constexpr int BATCH = 64;
constexpr int TLEN  = 2048;
constexpr int NIN   = 128;
constexpr int NHID  = 256;
constexpr int NOUT  = 128;
constexpr long MROWS = (long)BATCH * TLEN;   // 131072
constexpr float CSC = 2.8853900817779268f;   // 2*log2(e): 2^(CSC*z) = e^(2z)

__device__ __forceinline__ float exp2f_hw(float x) {
#if __has_builtin(__builtin_amdgcn_exp2f)
  return __builtin_amdgcn_exp2f(x);
#else
  return __expf(x * 0.6931471805599453f);
#endif
}
__device__ __forceinline__ float rcp_hw(float x) {
#if __has_builtin(__builtin_amdgcn_rcpf)
  return __builtin_amdgcn_rcpf(x);
#else
  return 1.0f / x;
#endif
}
__device__ __forceinline__ float fdot2f(unsigned int a, unsigned int b, float c) {
#if __has_builtin(__builtin_amdgcn_fdot2)
  return __builtin_amdgcn_fdot2(__builtin_bit_cast(f16x2, a),
                                __builtin_bit_cast(f16x2, b), c, false);
#else
  f16x2 av = __builtin_bit_cast(f16x2, a);
  f16x2 bv = __builtin_bit_cast(f16x2, b);
  return c + (float)av.x * (float)bv.x + (float)av.y * (float)bv.y;
#endif
}
// DPP: 0xB1 = quad_perm(1,0,3,2) -> lane^1 ; 0x4E = quad_perm(2,3,0,1) -> lane^2
template<int CTRL>
__device__ __forceinline__ float dpp_xor(float x) {
  int r = __builtin_amdgcn_update_dpp(0, __builtin_bit_cast(int, x),
                                      CTRL, 0xF, 0xF, true);
  return __builtin_bit_cast(float, r);
}
// barrier that makes LDS writes visible WITHOUT draining vmcnt (global
// stores / prefetch loads keep flying across steps)
__device__ __forceinline__ void barrier_lds() {
  asm volatile("s_waitcnt lgkmcnt(0)" ::: "memory");
  __builtin_amdgcn_s_barrier();
  asm volatile("" ::: "memory");
}

// ---------------------------------------------------------------------------
// Weight convert + hi/lo split. Whh pre-scaled by CSC (tanh exp2 fold).
// f16 layout: WinH[32768] WinL[32768] WihH[65536] WihL[65536] Whh[65536] Wout[32768]
// (unchanged, proven)
// ---------------------------------------------------------------------------
__global__ void cvt_weights(const float* __restrict__ Win, const float* __restrict__ Wih,
                            const float* __restrict__ Whh, const float* __restrict__ Wout,
                            f16* __restrict__ dst) {
  int i = blockIdx.x * blockDim.x + threadIdx.x;
  if (i < 32768) {
    float v = Win[i]; f16 h = (f16)v;
    dst[i] = h; dst[32768 + i] = (f16)(v - (float)h);
  } else if (i < 98304) {
    int j = i - 32768; float v = Wih[j]; f16 h = (f16)v;
    dst[65536 + j] = h; dst[131072 + j] = (f16)(v - (float)h);
  } else if (i < 163840) {
    int j = i - 98304; dst[196608 + j] = (f16)(CSC * Whh[j]);
  } else if (i < 196608) {
    int j = i - 163840; dst[262144 + j] = (f16)Wout[j];
  }
}

// ---------------------------------------------------------------------------
// GEMM: C[m,n] = act( sum_k A[m,k]*W[n,k] + bias[n] )
// R20 change: A-side lo path REMOVED (error analysis: x-quant term ~1.2e-4 is
// subdominant to W-quant ~5e-4, which stays corrected via B-side hi/lo).
//  MODE 1 (G1): A = f32 input staged as f16 hi only; B = W hi/lo (8 MFMA);
//               epilogue relu -> single f16 store (x_lo no longer produced).
//  MODE 2 (G2): A = f16 x_hi; B = W hi/lo (8 MFMA); epilogue CSC f32.
//  MODE 3 (G3): unchanged (A f16, B hi, 4 MFMA, plain f32 out).
// Saves: 1/3 of G1/G2 MFMAs, Al staging, 64MB x_lo write + 64MB x_lo read.
// ---------------------------------------------------------------------------
constexpr int BM = 64, BN = 64, BK = 64;

template<int MODE>
__global__ __launch_bounds__(256)
void gemm_kernel(const void* __restrict__ Ap,
                 const f16* __restrict__ Bh_, const f16* __restrict__ Bl_,
                 const float* __restrict__ bias, const float* __restrict__ bias2,
                 void* __restrict__ Cp, int K, int N) {
  __shared__ __align__(16) f16 Ah[BM][BK + 8];
  __shared__ __align__(16) f16 Bh[BN][BK + 8];
  __shared__ __align__(16) f16 Bl[BN][BK + 8];

  const int tid  = threadIdx.x;
  const int lane = tid & 63;
  const int wid  = tid >> 6;
  const int wm = wid >> 1, wn = wid & 1;
  const long row0 = (long)blockIdx.x * BM;
  const int  col0 = blockIdx.y * BN;
  const int r  = tid >> 2;
  const int cc = (tid & 3) * 16;

  f32x4 acc[2][2] = {};

  for (int k0 = 0; k0 < K; k0 += BK) {
    if constexpr (MODE == 1) {
      const float* src = (const float*)Ap + (row0 + r) * (long)K + k0 + cc;
      #pragma unroll
      for (int q = 0; q < 4; ++q) {
        float4 v = ((const float4*)src)[q];
        Ah[r][cc + 4*q + 0] = (f16)v.x;
        Ah[r][cc + 4*q + 1] = (f16)v.y;
        Ah[r][cc + 4*q + 2] = (f16)v.z;
        Ah[r][cc + 4*q + 3] = (f16)v.w;
      }
    } else {
      const f16* sh = (const f16*)Ap + (row0 + r) * (long)K + k0 + cc;
      *(uint4*)&Ah[r][cc]     = *(const uint4*)sh;
      *(uint4*)&Ah[r][cc + 8] = *(const uint4*)(sh + 8);
    }
    {
      const f16* sh = Bh_ + (col0 + r) * (long)K + k0 + cc;
      *(uint4*)&Bh[r][cc]     = *(const uint4*)sh;
      *(uint4*)&Bh[r][cc + 8] = *(const uint4*)(sh + 8);
      if constexpr (MODE != 3) {
        const f16* sl = Bl_ + (col0 + r) * (long)K + k0 + cc;
        *(uint4*)&Bl[r][cc]     = *(const uint4*)sl;
        *(uint4*)&Bl[r][cc + 8] = *(const uint4*)(sl + 8);
      }
    }
    __syncthreads();

    #pragma unroll
    for (int ks = 0; ks < BK / 32; ++ks) {
      const int ko = ks * 32 + (lane >> 4) * 8;
      const int ra = wm * 32 + (lane & 15);
      const int rb = wn * 32 + (lane & 15);
      f16x8 a0 = *(const f16x8*)&Ah[ra][ko];
      f16x8 a1 = *(const f16x8*)&Ah[ra + 16][ko];
      f16x8 b0 = *(const f16x8*)&Bh[rb][ko];
      f16x8 b1 = *(const f16x8*)&Bh[rb + 16][ko];
      acc[0][0] = __builtin_amdgcn_mfma_f32_16x16x32_f16(a0, b0, acc[0][0], 0, 0, 0);
      acc[0][1] = __builtin_amdgcn_mfma_f32_16x16x32_f16(a0, b1, acc[0][1], 0, 0, 0);
      acc[1][0] = __builtin_amdgcn_mfma_f32_16x16x32_f16(a1, b0, acc[1][0], 0, 0, 0);
      acc[1][1] = __builtin_amdgcn_mfma_f32_16x16x32_f16(a1, b1, acc[1][1], 0, 0, 0);
      if constexpr (MODE != 3) {
        f16x8 lb0 = *(const f16x8*)&Bl[rb][ko];
        f16x8 lb1 = *(const f16x8*)&Bl[rb + 16][ko];
        acc[0][0] = __builtin_amdgcn_mfma_f32_16x16x32_f16(a0, lb0, acc[0][0], 0, 0, 0);
        acc[0][1] = __builtin_amdgcn_mfma_f32_16x16x32_f16(a0, lb1, acc[0][1], 0, 0, 0);
        acc[1][0] = __builtin_amdgcn_mfma_f32_16x16x32_f16(a1, lb0, acc[1][0], 0, 0, 0);
        acc[1][1] = __builtin_amdgcn_mfma_f32_16x16x32_f16(a1, lb1, acc[1][1], 0, 0, 0);
      }
    }
    __syncthreads();
  }

  #pragma unroll
  for (int mi = 0; mi < 2; ++mi)
    #pragma unroll
    for (int ni = 0; ni < 2; ++ni)
      #pragma unroll
      for (int q = 0; q < 4; ++q) {
        long row = row0 + wm * 32 + mi * 16 + (lane >> 4) * 4 + q;
        int  col = col0 + wn * 32 + ni * 16 + (lane & 15);
        if constexpr (MODE == 1) {
          float v = fmaxf(acc[mi][ni][q] + bias[col], 0.0f);
          ((f16*)Cp)[row * (long)N + col] = (f16)v;
        } else if constexpr (MODE == 2) {
          float v = (acc[mi][ni][q] + bias[col] + bias2[col]) * CSC;
          ((float*)Cp)[row * (long)N + col] = v;
        } else {
          ((float*)Cp)[row * (long)N + col] = acc[mi][ni][q] + bias[col];
        }
      }
}

// ---------------------------------------------------------------------------
// Recurrence: VERBATIM R12 (the session-best 887us kernel, VGPR 48).
// Post-R19 verdict: weight register-residency is unreachable from HIP source
// on this compiler (R16-R19: VGPR 32-80 regardless of pins/bounds/aliasing;
// MFMA variants add copy storms). R12's 1039 cyc/step already co-schedules
// the L2 weight re-stream (~570 cyc @64 CUs) under the fdot2 issue + serial
// chain; every restructure lost to it. Do not touch.
// 64 blocks x 512 threads. jj = lane&3 owns k [64jj,64jj+64);
// grp = (lane>>2)|(w<<4) owns outputs {2grp,2grp+1}. Reduce: xor1 keep/send
// + xor2 all-reduce (quad_perm DPP only). Dup pair (l,l^2): s1=0 lane writes
// LDS h, s1=1 lane writes h16 global (one store per lane).
// Chunk-rotated LDS reads (R4-measured: 0 bank conflicts).
// barrier_lds(): lgkmcnt-only. No pin/waves attrs (R4 codegen was fastest).
// ---------------------------------------------------------------------------
#define STEP(K, SRC, DST, P) do {                                            \
  unsigned int hs[32];                                                       \
  _Pragma("unroll")                                                          \
  for (int q = 0; q < 8; ++q) {                                              \
    uint4 v = *(const uint4*)((SRC) + roff[q]);                              \
    hs[4*q+0] = v.x; hs[4*q+1] = v.y; hs[4*q+2] = v.z; hs[4*q+3] = v.w;      \
  }                                                                          \
  float a0a = 0.f, a1a = 0.f, a0b = 0.f, a1b = 0.f;                          \
  _Pragma("unroll")                                                          \
  for (int kk = 0; kk < 16; ++kk) {                                          \
    a0a = fdot2f(wr0[kk], hs[kk], a0a);                                      \
    a1a = fdot2f(wr1[kk], hs[kk], a1a);                                      \
  }                                                                          \
  _Pragma("unroll")                                                          \
  for (int kk = 16; kk < 32; ++kk) {                                         \
    a0b = fdot2f(wr0[kk], hs[kk], a0b);                                      \
    a1b = fdot2f(wr1[kk], hs[kk], a1b);                                      \
  }                                                                          \
  float a0 = a0a + a0b, a1 = a1a + a1b;                                      \
  float keep = s0 ? a1 : a0;                                                 \
  float send = s0 ? a0 : a1;                                                 \
  float t1 = keep + dpp_xor<0xB1>(send);    /* xor1, quad_perm(1,0,3,2) */   \
  float z  = t1 + dpp_xor<0x4E>(t1) + (P);  /* xor2 all-reduce */            \
  float ee = exp2f_hw(z);                                                    \
  float hv = fmaxf(fmaf(-2.0f, rcp_hw(ee + 1.0f), 1.0f), 0.0f);              \
  f16 hf = (f16)hv;                                                          \
  if (!s1) *(f16*)((DST) + wo) = hf;        /* LDS next-h (one copy) */      \
  else     hp[(K) * 256] = hf;              /* h16 global (other copy) */    \
} while (0)

__global__ __launch_bounds__(512, 1)
void rec_kernel(const float* __restrict__ pre, const f16* __restrict__ W2,
                f16* __restrict__ h16) {
  const int b    = blockIdx.x;
  const int tid  = threadIdx.x;
  const int lane = tid & 63;
  const int w    = tid >> 6;                 // 0..7
  const int jj   = lane & 3;                 // k-slice [64jj,64jj+64)
  const int grp  = (lane >> 2) | (w << 4);   // 0..127
  const int s0   = lane & 1;
  const int s1   = (lane >> 1) & 1;
  const int G    = grp * 2;
  const int g    = G + s0;                   // owned output (dup with lane^2)

  __shared__ __align__(16) char hb[2][512];

  // W rows G, G+1, k in [64jj,64jj+64), chunk-rotated to match LDS reads
  unsigned int wr0[32], wr1[32];
  #pragma unroll
  for (int q = 0; q < 8; ++q) {
    int c = (q + 2 * jj) & 7;
    uint4 v0 = *(const uint4*)(W2 + (size_t)G * 256 + 64 * jj + 8 * c);
    uint4 v1 = *(const uint4*)(W2 + (size_t)(G + 1) * 256 + 64 * jj + 8 * c);
    wr0[4*q+0] = v0.x; wr0[4*q+1] = v0.y; wr0[4*q+2] = v0.z; wr0[4*q+3] = v0.w;
    wr1[4*q+0] = v1.x; wr1[4*q+1] = v1.y; wr1[4*q+2] = v1.z; wr1[4*q+3] = v1.w;
  }
  if (tid < 128) ((unsigned int*)&hb[0][0])[tid] = 0u;
  __syncthreads();

  int roff[8];
  #pragma unroll
  for (int q = 0; q < 8; ++q) roff[q] = 128 * jj + 16 * ((q + 2 * jj) & 7);
  const int wo = 2 * g;

  const float* pp  = pre + (size_t)b * TLEN * 256 + g;
  f16*         hp  = h16 + (size_t)b * TLEN * 256 + g;
  const float* ppf = pp + 1024;              // t+4 prefetch pointer

  float p0 = pp[0];
  float p1 = pp[256];
  float p2 = pp[512];
  float p3 = pp[768];

  const char* hb0 = &hb[0][0];
  char*       hb1 = &hb[1][0];

  #pragma unroll 1
  for (int t = 0; t < TLEN; t += 4) {
    // issue next-quad prefetch early; lands during these 4 steps
    float n0 = ppf[0];
    float n1 = ppf[256];
    float n2 = ppf[512];
    float n3 = ppf[768];
    STEP(0, hb0, hb1, p0);
    barrier_lds();
    STEP(1, hb1, (char*)hb0, p1);
    barrier_lds();
    STEP(2, hb0, hb1, p2);
    barrier_lds();
    STEP(3, hb1, (char*)hb0, p3);
    barrier_lds();
    p0 = n0; p1 = n1; p2 = n2; p3 = n3;
    ppf += 1024;
    hp  += 1024;
  }
}

// ---------------------------------------------------------------------------
// h16 -> f32 hidden (parallel, HBM-bound; removes the f32 store from rec's
// serial loop). Proven in R2.
// ---------------------------------------------------------------------------
__global__ __launch_bounds__(256)
void cvt_h(const f16* __restrict__ src, float* __restrict__ dst, long n) {
  long i0 = ((long)blockIdx.x * 256 + threadIdx.x) * 8;
  long stride = (long)gridDim.x * 256 * 8;
  for (long i = i0; i < n; i += stride) {
    f16x8 v = *(const f16x8*)(src + i);
    float4 a = {(float)v[0], (float)v[1], (float)v[2], (float)v[3]};
    float4 bq = {(float)v[4], (float)v[5], (float)v[6], (float)v[7]};
    *(float4*)(dst + i) = a;
    *(float4*)(dst + i + 4) = bq;
  }
}

// ---------------------------------------------------------------------------
extern "C" void kernel_launch(void* const* d_in, const int* in_sizes, int n_in,
                              void* d_out, int out_size, void* d_ws, size_t ws_size,
                              hipStream_t stream) {
  const float* input = (const float*)d_in[0];
  const float* W_in  = (const float*)d_in[1];
  const float* b_in  = (const float*)d_in[2];
  const float* W_ih  = (const float*)d_in[3];
  const float* b_ih  = (const float*)d_in[4];
  const float* W_hh  = (const float*)d_in[5];
  const float* b_hh  = (const float*)d_in[6];
  const float* W_out = (const float*)d_in[7];
  const float* b_out = (const float*)d_in[8];

  float* hidden = (float*)d_out;                   // [64,2048,256] f32
  float* outp   = (float*)d_out + MROWS * NHID;    // [64,2048,128] f32

  char* ws = (char*)d_ws;
  const size_t xh_off  = 0;
  const size_t xl_off  = (size_t)MROWS * NHID * 2;       // 64 MiB (unused now)
  const size_t pre_off = xl_off * 2;                     // 128 MiB in
  const size_t w_off   = pre_off + (size_t)MROWS * NHID * 4;
  const size_t need    = w_off + 294912ull * 2;
  if (ws_size < need) return;

  f16*   x_hi  = (f16*)(ws + xh_off);
  float* pre   = (float*)(ws + pre_off);                 // plain [b][t][g], scaled
  f16*   wbase = (f16*)(ws + w_off);
  f16 *WinH = wbase,           *WinL = wbase + 32768;
  f16 *WihH = wbase + 65536,   *WihL = wbase + 131072;
  f16 *Whh16 = wbase + 196608, *Wout16 = wbase + 262144;
  f16* h16 = x_hi;   // alias: x consumed by G2 before rec writes h16

  cvt_weights<<<768, 256, 0, stream>>>(W_in, W_ih, W_hh, W_out, wbase);

  dim3 g12((unsigned)(MROWS / BM), NHID / BN);
  gemm_kernel<1><<<g12, 256, 0, stream>>>(input, WinH, WinL, b_in, nullptr,
                                          x_hi, NIN, NHID);
  gemm_kernel<2><<<g12, 256, 0, stream>>>(x_hi, WihH, WihL, b_ih, b_hh,
                                          pre, NHID, NHID);

  rec_kernel<<<BATCH, 512, 0, stream>>>(pre, Whh16, h16);

  cvt_h<<<2048, 256, 0, stream>>>(h16, hidden, MROWS * NHID);

  dim3 g3((unsigned)(MROWS / BM), NOUT / BN);
  gemm_kernel<3><<<g3, 256, 0, stream>>>(h16, Wout16, nullptr, b_out, nullptr,
                                         outp, NHID, NOUT);
}